// Round 14
// baseline (633.667 us; speedup 1.0000x reference)
//
#include <hip/hip_runtime.h>
#include <stdint.h>
#include <math.h>

typedef unsigned short u16;
typedef unsigned int u32;
typedef __attribute__((ext_vector_type(8))) short bf16x8;
typedef __attribute__((ext_vector_type(4))) float f32x4;

#define SEQ 2048
#define HID 2048
#define NH  16
#define DH  128
#define NB  2

typedef __attribute__((address_space(1))) const u32 gu32;
typedef __attribute__((address_space(3))) u32 lu32;

__device__ __forceinline__ u16 f2bf(float f) {
  u32 u = __float_as_uint(f);
  return (u16)((u + 0x7fffu + ((u >> 16) & 1u)) >> 16);
}
__device__ __forceinline__ float bf2f(u16 h) { return __uint_as_float(((u32)h) << 16); }

__device__ __forceinline__ void gload_lds16(const void* g, void* l) {
  __builtin_amdgcn_global_load_lds((gu32*)g, (lu32*)l, 16, 0, 0);
}

// ---------------- fused fp32 -> bf16 convert (3 regions, 1 launch) ----------------
__global__ __launch_bounds__(256) void k_cvt3(const float* __restrict__ s0, u16* __restrict__ d0, int n0,
                                              const float* __restrict__ s1, u16* __restrict__ d1, int n1,
                                              const float* __restrict__ s2, u16* __restrict__ d2, int n2) {
  int i = blockIdx.x * 256 + threadIdx.x;
  int stride = gridDim.x * 256;
  int total = n0 + n1 + n2;
  for (; i < total; i += stride) {
    const float* s; u16* d; int k = i;
    if (k < n0) { s = s0; d = d0; }
    else if (k < n0 + n1) { s = s1; d = d1; k -= n0; }
    else { s = s2; d = d2; k -= n0 + n1; }
    float4 v = ((const float4*)s)[k];
    ushort4 o;
    o.x = f2bf(v.x); o.y = f2bf(v.y); o.z = f2bf(v.z); o.w = f2bf(v.w);
    ((ushort4*)d)[k] = o;
  }
}

// ---------------- GEMM C = A * B^T  (A:[M,K], B:[N,K], bf16 in, fp32 acc) ----------------
template<int EPI>
__global__ __launch_bounds__(256)
void k_gemm(const u16* __restrict__ A, const u16* __restrict__ Bm,
            float* __restrict__ Cf, u16* __restrict__ Qr, u16* __restrict__ Kr, u16* __restrict__ Vr,
            int N, int K, int NX) {
  __shared__ alignas(16) char sA[128 * 128];
  __shared__ alignas(16) char sB[128 * 128];
  const int tid = threadIdx.x;
  const int wid = tid >> 6, lane = tid & 63;
  const int l15 = lane & 15, l4 = lane >> 4;
  const int nwg = gridDim.x, bid = blockIdx.x;
  const int wg = (bid & 7) * (nwg >> 3) + (bid >> 3);
  const int bx = wg % NX, by = wg / NX;
  const int m0 = by * 128, n0 = bx * 128;
  const int wr = (wid >> 1) * 64, wc = (wid & 1) * 64;

  f32x4 acc[4][4];
  #pragma unroll
  for (int i = 0; i < 4; ++i)
    #pragma unroll
    for (int j = 0; j < 4; ++j)
      acc[i][j] = (f32x4){0.f, 0.f, 0.f, 0.f};

  const int nkt = K >> 6;
  for (int kt = 0; kt < nkt; ++kt) {
    const int k0 = kt << 6;
    __syncthreads();
    #pragma unroll
    for (int it = 0; it < 4; ++it) {
      int o = it * 4096 + tid * 16;
      int row = o >> 7, cb = o & 127;
      int scb = cb ^ ((row & 7) << 4);
      gload_lds16((const char*)A + ((size_t)(m0 + row) * K + k0) * 2 + scb, &sA[it * 4096 + wid * 1024]);
    }
    #pragma unroll
    for (int it = 0; it < 4; ++it) {
      int o = it * 4096 + tid * 16;
      int row = o >> 7, cb = o & 127;
      int scb = cb ^ ((row & 7) << 4);
      gload_lds16((const char*)Bm + ((size_t)(n0 + row) * K + k0) * 2 + scb, &sB[it * 4096 + wid * 1024]);
    }
    __syncthreads();
    #pragma unroll
    for (int kk = 0; kk < 2; ++kk) {
      bf16x8 av[4], bv[4];
      #pragma unroll
      for (int mi = 0; mi < 4; ++mi) {
        int row = wr + mi * 16 + l15;
        int colb = kk * 64 + 16 * l4;
        av[mi] = *(const bf16x8*)&sA[row * 128 + (colb ^ ((row & 7) << 4))];
      }
      #pragma unroll
      for (int ni = 0; ni < 4; ++ni) {
        int row = wc + ni * 16 + l15;
        int colb = kk * 64 + 16 * l4;
        bv[ni] = *(const bf16x8*)&sB[row * 128 + (colb ^ ((row & 7) << 4))];
      }
      #pragma unroll
      for (int mi = 0; mi < 4; ++mi)
        #pragma unroll
        for (int ni = 0; ni < 4; ++ni)
          acc[mi][ni] = __builtin_amdgcn_mfma_f32_16x16x32_bf16(av[mi], bv[ni], acc[mi][ni], 0, 0, 0);
    }
  }

  #pragma unroll
  for (int mi = 0; mi < 4; ++mi) {
    #pragma unroll
    for (int ni = 0; ni < 4; ++ni) {
      #pragma unroll
      for (int j = 0; j < 4; ++j) {
        int gm = m0 + wr + mi * 16 + l4 * 4 + j;
        int gn = n0 + wc + ni * 16 + l15;
        float v = acc[mi][ni][j];
        if (EPI == 0) {
          int b = gm >> 11, l = gm & 2047;
          int which = gn >> 11, hid = gn & 2047;
          int h = hid >> 7, d = hid & 127;
          u16* dst = (which == 0) ? Qr : ((which == 1) ? Kr : Vr);
          size_t idx = ((size_t)(b * NH + h) * SEQ + l) * DH + d;
          dst[idx] = f2bf(v);
        } else {
          Cf[(size_t)gm * N + gn] = v;
        }
      }
    }
  }
}

// ---------------- V transpose: Vr[bh][l][d] -> Vt[bh][d][l] ----------------
__global__ __launch_bounds__(256) void k_vtr(const u16* __restrict__ Vr, u16* __restrict__ Vt) {
  __shared__ u16 tile[64][72];
  const int k0 = blockIdx.x * 64, d0 = blockIdx.y * 64, bh = blockIdx.z;
  const u16* src = Vr + ((size_t)bh << 18);
  u16* dst = Vt + ((size_t)bh << 18);
  const int tid = threadIdx.x;
  #pragma unroll
  for (int it = 0; it < 2; ++it) {
    int e = it * 2048 + tid * 8;
    int r = e >> 6, c = e & 63;
    bf16x8 v = *(const bf16x8*)(src + (size_t)(k0 + r) * DH + d0 + c);
    *(bf16x8*)&tile[r][c] = v;
  }
  __syncthreads();
  #pragma unroll
  for (int it = 0; it < 2; ++it) {
    int e = it * 2048 + tid * 8;
    int rd = e >> 6, ck = e & 63;
    bf16x8 w;
    #pragma unroll
    for (int i = 0; i < 8; ++i) w[i] = (short)tile[ck + i][rd];
    *(bf16x8*)(dst + (size_t)(d0 + rd) * SEQ + k0 + ck) = w;
  }
}

// -------- RMSNorm + interleaved RoPE, in place; blockIdx.y: 0 -> Q (mul=mq), 1 -> K --------
__global__ __launch_bounds__(256) void k_nrope2(u16* __restrict__ Qr, u16* __restrict__ Kr, float mq) {
  u16* T = blockIdx.y ? Kr : Qr;
  const float mul = blockIdx.y ? 1.0f : mq;
  const int r = blockIdx.x * 4 + (threadIdx.x >> 6);
  const int lane = threadIdx.x & 63;
  u16* p = T + ((size_t)r << 7) + lane * 2;
  u32 pr = *(const u32*)p;
  float xe = bf2f((u16)(pr & 0xffffu));
  float xo = bf2f((u16)(pr >> 16));
  float ss = xe * xe + xo * xo;
  #pragma unroll
  for (int off = 1; off < 64; off <<= 1) ss += __shfl_xor(ss, off);
  float rinv = rsqrtf(ss * (1.f / 128.f) + 1e-5f);
  float e = xe * rinv, o = xo * rinv;
  int pos = r & (SEQ - 1);
  float freq = exp2f(-0.20762050593046014f * (float)lane);
  float ang = (float)pos * freq;
  float sn, cs;
  sincosf(ang, &sn, &cs);
  u32 outw = (u32)f2bf((o * cs - e * sn) * mul) | ((u32)f2bf((o * sn + e * cs) * mul) << 16);
  *(u32*)p = outw;
}

// ---------------- causal flash attention: single-buffered LDS, 4 blocks/CU ----------------
__device__ __forceinline__ void smax(f32x4 (&sacc)[4], float& m_, float& se,
                                     f32x4* accO, u32 (&pw)[8],
                                     bool diag, int qpos, int kb, int l15, int l4) {
  if (diag) {
    #pragma unroll
    for (int sj = 0; sj < 4; ++sj)
      #pragma unroll
      for (int j = 0; j < 4; ++j) {
        int kpos = kb + sj * 16 + l4 * 4 + j;
        if (kpos > qpos) sacc[sj][j] = -1e30f;
      }
  }
  float mx = sacc[0][0];
  #pragma unroll
  for (int sj = 0; sj < 4; ++sj)
    #pragma unroll
    for (int j = 0; j < 4; ++j) mx = fmaxf(mx, sacc[sj][j]);
  mx = fmaxf(mx, __shfl_xor(mx, 16));
  mx = fmaxf(mx, __shfl_xor(mx, 32));
  if (!__all(mx <= m_ + 8.f)) {
    float mn = fmaxf(m_, mx);
    float corr = __builtin_exp2f(m_ - mn);
    m_ = mn;
    se *= corr;
    float corr4[4];
    #pragma unroll
    for (int j = 0; j < 4; ++j) corr4[j] = __shfl(corr, l4 * 4 + j);
    #pragma unroll
    for (int db = 0; db < 8; ++db) {
      f32x4 a = accO[db];
      #pragma unroll
      for (int j = 0; j < 4; ++j) a[j] *= corr4[j];
      accO[db] = a;
    }
  }
  float sum = 0.f;
  #pragma unroll
  for (int sj = 0; sj < 4; ++sj)
    #pragma unroll
    for (int jp = 0; jp < 2; ++jp) {
      float p0 = __builtin_exp2f(sacc[sj][jp * 2]     - m_);
      float p1 = __builtin_exp2f(sacc[sj][jp * 2 + 1] - m_);
      pw[sj * 2 + jp] = (u32)f2bf(p0) | ((u32)f2bf(p1) << 16);
      sum += p0 + p1;
    }
  sum += __shfl_xor(sum, 16);
  sum += __shfl_xor(sum, 32);
  se += sum;
}

__device__ __forceinline__ void pwrite(char* sPw, const u32 (&pw)[8], int l15, int l4) {
  const int sw = (l15 & 7) << 4;
  char* base = sPw + l15 * 128;
  #pragma unroll
  for (int sj = 0; sj < 4; ++sj)
    #pragma unroll
    for (int jp = 0; jp < 2; ++jp)
      *(u32*)(base + ((sj * 32 + l4 * 8 + jp * 4) ^ sw)) = pw[sj * 2 + jp];
}

__device__ __forceinline__ void stage_kv(const char* Kp, const char* Vtp, int kb,
                                         char* bK, char* bV, int tid, int wid) {
  #pragma unroll
  for (int it = 0; it < 4; ++it) {
    int o = it * 4096 + tid * 16;
    int row = o >> 8, cb = o & 255;
    int scb = cb ^ ((row & 7) << 4);
    gload_lds16(Kp + (size_t)(kb + row) * 256 + scb, &bK[it * 4096 + wid * 1024]);
  }
  #pragma unroll
  for (int it = 0; it < 4; ++it) {
    int o = it * 4096 + tid * 16;
    int row = o >> 7, cb = o & 127;
    int scb = cb ^ ((row & 7) << 4);
    gload_lds16(Vtp + (size_t)row * (SEQ * 2) + kb * 2 + scb, &bV[it * 4096 + wid * 1024]);
  }
}

// grid: 512 blocks (XCD-remapped); block 256 = 4 waves; 4 blocks/CU (40KB LDS).
__global__ __launch_bounds__(256, 4)
void k_attn(const u16* __restrict__ Q, const u16* __restrict__ Kg,
            const u16* __restrict__ Vt, u16* __restrict__ O) {
  __shared__ alignas(16) char sK[64 * 256];
  __shared__ alignas(16) char sV[128 * 128];
  __shared__ alignas(16) char sP[4 * 2048];
  const int tid = threadIdx.x, wid = tid >> 6, lane = tid & 63;
  const int l15 = lane & 15, l4 = lane >> 4;
  const int i = blockIdx.x;
  const int xcd = i & 7, slot = i >> 3;
  const int p = slot & 15;
  const int bh = xcd + 8 * (slot >> 4);
  const int b = bh >> 4, h = bh & 15;
  const int tA = p, tB = 31 - p;
  const u16* Qp = Q + ((size_t)bh << 18);
  const char* Kp = (const char*)(Kg + ((size_t)bh << 18));
  const char* Vtp = (const char*)(Vt + ((size_t)bh << 18));
  const int q0A = tA * 64 + wid * 16;
  const int q0B = tB * 64 + wid * 16;

  bf16x8 aqA[4], aqB[4];
  #pragma unroll
  for (int kk = 0; kk < 4; ++kk) {
    aqA[kk] = *(const bf16x8*)(Qp + (size_t)(q0A + l15) * DH + kk * 32 + 8 * l4);
    aqB[kk] = *(const bf16x8*)(Qp + (size_t)(q0B + l15) * DH + kk * 32 + 8 * l4);
  }

  f32x4 accA[8], accB[8];
  #pragma unroll
  for (int i2 = 0; i2 < 8; ++i2) { accA[i2] = (f32x4){0.f,0.f,0.f,0.f}; accB[i2] = (f32x4){0.f,0.f,0.f,0.f}; }
  float mA = -1e30f, mB = -1e30f, seA = 0.f, seB = 0.f;

  char* sPw = sP + wid * 2048;
  const int psw = (l15 & 7) << 4;
  const int nt = tB + 1;

  for (int t = 0; t < nt; ++t) {
    __syncthreads();   // previous iteration done reading LDS
    stage_kv(Kp, Vtp, t << 6, sK, sV, tid, wid);
    __syncthreads();   // compiler drains vmcnt(0) before barrier -> data ready

    const int kb = t << 6;
    if (t <= tA) {
      // ---- dual path: both sub-tiles, shared K/V operands ----
      f32x4 sb[4], sa[4];
      __builtin_amdgcn_s_setprio(1);
      #pragma unroll
      for (int sj = 0; sj < 4; ++sj) {
        sb[sj] = (f32x4){0.f,0.f,0.f,0.f};
        sa[sj] = (f32x4){0.f,0.f,0.f,0.f};
        int row = sj * 16 + l15;
        const char* rK = sK + (row << 8);
        int swr = (row & 7) << 4;
        #pragma unroll
        for (int kk = 0; kk < 4; ++kk) {
          bf16x8 bkv = *(const bf16x8*)(rK + ((kk * 64 + 16 * l4) ^ swr));
          sb[sj] = __builtin_amdgcn_mfma_f32_16x16x32_bf16(bkv, aqB[kk], sb[sj], 0, 0, 0);
          sa[sj] = __builtin_amdgcn_mfma_f32_16x16x32_bf16(bkv, aqA[kk], sa[sj], 0, 0, 0);
        }
      }
      __builtin_amdgcn_s_setprio(0);
      u32 pwB[8], pwA[8];
      smax(sb, mB, seB, accB, pwB, false, 0, kb, l15, l4);
      smax(sa, mA, seA, accA, pwA, t == tA, q0A + l15, kb, l15, l4);
      pwrite(sPw, pwB, l15, l4);
      bf16x8 paB0 = *(const bf16x8*)(sPw + l15 * 128 + ((16 * l4) ^ psw));
      bf16x8 paB1 = *(const bf16x8*)(sPw + l15 * 128 + ((64 + 16 * l4) ^ psw));
      pwrite(sPw, pwA, l15, l4);
      bf16x8 paA0 = *(const bf16x8*)(sPw + l15 * 128 + ((16 * l4) ^ psw));
      bf16x8 paA1 = *(const bf16x8*)(sPw + l15 * 128 + ((64 + 16 * l4) ^ psw));
      __builtin_amdgcn_s_setprio(1);
      #pragma unroll
      for (int db = 0; db < 8; ++db) {
        int row = db * 16 + l15;
        const char* vb = sV + row * 128;
        int swr = (row & 7) << 4;
        bf16x8 b0 = *(const bf16x8*)(vb + ((16 * l4) ^ swr));
        bf16x8 b1 = *(const bf16x8*)(vb + ((64 + 16 * l4) ^ swr));
        accB[db] = __builtin_amdgcn_mfma_f32_16x16x32_bf16(paB0, b0, accB[db], 0, 0, 0);
        accA[db] = __builtin_amdgcn_mfma_f32_16x16x32_bf16(paA0, b0, accA[db], 0, 0, 0);
        accB[db] = __builtin_amdgcn_mfma_f32_16x16x32_bf16(paB1, b1, accB[db], 0, 0, 0);
        accA[db] = __builtin_amdgcn_mfma_f32_16x16x32_bf16(paA1, b1, accA[db], 0, 0, 0);
      }
      __builtin_amdgcn_s_setprio(0);
    } else {
      // ---- single path: B only ----
      f32x4 sb[4];
      __builtin_amdgcn_s_setprio(1);
      #pragma unroll
      for (int sj = 0; sj < 4; ++sj) {
        sb[sj] = (f32x4){0.f,0.f,0.f,0.f};
        int row = sj * 16 + l15;
        const char* rK = sK + (row << 8);
        int swr = (row & 7) << 4;
        #pragma unroll
        for (int kk = 0; kk < 4; ++kk) {
          bf16x8 bkv = *(const bf16x8*)(rK + ((kk * 64 + 16 * l4) ^ swr));
          sb[sj] = __builtin_amdgcn_mfma_f32_16x16x32_bf16(bkv, aqB[kk], sb[sj], 0, 0, 0);
        }
      }
      __builtin_amdgcn_s_setprio(0);
      u32 pwB[8];
      smax(sb, mB, seB, accB, pwB, t == tB, q0B + l15, kb, l15, l4);
      pwrite(sPw, pwB, l15, l4);
      bf16x8 paB0 = *(const bf16x8*)(sPw + l15 * 128 + ((16 * l4) ^ psw));
      bf16x8 paB1 = *(const bf16x8*)(sPw + l15 * 128 + ((64 + 16 * l4) ^ psw));
      __builtin_amdgcn_s_setprio(1);
      #pragma unroll
      for (int db = 0; db < 8; ++db) {
        int row = db * 16 + l15;
        const char* vb = sV + row * 128;
        int swr = (row & 7) << 4;
        bf16x8 b0 = *(const bf16x8*)(vb + ((16 * l4) ^ swr));
        bf16x8 b1 = *(const bf16x8*)(vb + ((64 + 16 * l4) ^ swr));
        accB[db] = __builtin_amdgcn_mfma_f32_16x16x32_bf16(paB0, b0, accB[db], 0, 0, 0);
        accB[db] = __builtin_amdgcn_mfma_f32_16x16x32_bf16(paB1, b1, accB[db], 0, 0, 0);
      }
      __builtin_amdgcn_s_setprio(0);
    }
  }

  float seA4[4], seB4[4];
  #pragma unroll
  for (int j = 0; j < 4; ++j) {
    seA4[j] = __shfl(seA, l4 * 4 + j);
    seB4[j] = __shfl(seB, l4 * 4 + j);
  }
  #pragma unroll
  for (int db = 0; db < 8; ++db) {
    #pragma unroll
    for (int j = 0; j < 4; ++j) {
      int d = db * 16 + l15;
      int qA = q0A + l4 * 4 + j;
      int qB = q0B + l4 * 4 + j;
      O[(size_t)(b * SEQ + qA) * HID + h * DH + d] = f2bf(accA[db][j] / seA4[j]);
      O[(size_t)(b * SEQ + qB) * HID + h * DH + d] = f2bf(accB[db][j] / seB4[j]);
    }
  }
}

extern "C" void kernel_launch(void* const* d_in, const int* in_sizes, int n_in,
                              void* d_out, int out_size, void* d_ws, size_t ws_size,
                              hipStream_t stream) {
  (void)in_sizes; (void)n_in; (void)out_size; (void)ws_size;
  const float* x = (const float*)d_in[0];
  const float* Wqkv = (const float*)d_in[1];
  const float* Wout = (const float*)d_in[2];
  float* out = (float*)d_out;
  char* ws = (char*)d_ws;

  u16* xb  = (u16*)(ws);                                   // 16 MB [4096][2048] bf16 (also attn O)
  u16* wqb = (u16*)(ws + (size_t)16777216);                // 24 MB [6144][2048] bf16
  u16* Vt  = wqb;                                          // aliases wqb AFTER gemm0 (16 MB)
  u16* wob = (u16*)(ws + (size_t)16777216 + 25165824);     // 8 MB  [2048][2048] bf16
  u16* Qr  = (u16*)(ws + (size_t)50331648);                // 16 MB each (8388608 u16 elements)
  u16* Kr  = Qr + (size_t)8388608;
  u16* Vr  = Kr + (size_t)8388608;
  u16* Ob  = xb;

  const float mq = 0.08838834764831845f * 1.4426950408889634f;

  k_cvt3<<<dim3(2048), dim3(256), 0, stream>>>(x, xb, (NB * SEQ * HID) / 4,
                                               Wqkv, wqb, (3 * HID * HID) / 4,
                                               Wout, wob, (HID * HID) / 4);

  k_gemm<0><<<dim3(1536), dim3(256), 0, stream>>>(xb, wqb, nullptr, Qr, Kr, Vr, 3 * HID, HID, 48);

  k_vtr<<<dim3(SEQ / 64, DH / 64, NB * NH), dim3(256), 0, stream>>>(Vr, Vt);
  k_nrope2<<<dim3((NB * NH * SEQ) / 4, 2), dim3(256), 0, stream>>>(Qr, Kr, mq);

  k_attn<<<dim3(512), dim3(256), 0, stream>>>(Qr, Kr, Vt, Ob);

  k_gemm<1><<<dim3(512), dim3(256), 0, stream>>>(Ob, wob, out, nullptr, nullptr, nullptr, HID, HID, 16);
}

// Round 15
// 298.845 us; speedup vs baseline: 2.1204x; 2.1204x over previous
//
#include <hip/hip_runtime.h>
#include <stdint.h>
#include <math.h>

typedef unsigned short u16;
typedef unsigned int u32;
typedef __attribute__((ext_vector_type(8))) short bf16x8;
typedef __attribute__((ext_vector_type(4))) float f32x4;

#define SEQ 2048
#define HID 2048
#define NH  16
#define DH  128
#define NB  2

typedef __attribute__((address_space(1))) const u32 gu32;
typedef __attribute__((address_space(3))) u32 lu32;

__device__ __forceinline__ u16 f2bf(float f) {
  u32 u = __float_as_uint(f);
  return (u16)((u + 0x7fffu + ((u >> 16) & 1u)) >> 16);
}
__device__ __forceinline__ float bf2f(u16 h) { return __uint_as_float(((u32)h) << 16); }

__device__ __forceinline__ void gload_lds16(const void* g, void* l) {
  __builtin_amdgcn_global_load_lds((gu32*)g, (lu32*)l, 16, 0, 0);
}

// ---------------- fused fp32 -> bf16 convert (3 regions, 1 launch) ----------------
__global__ __launch_bounds__(256) void k_cvt3(const float* __restrict__ s0, u16* __restrict__ d0, int n0,
                                              const float* __restrict__ s1, u16* __restrict__ d1, int n1,
                                              const float* __restrict__ s2, u16* __restrict__ d2, int n2) {
  int i = blockIdx.x * 256 + threadIdx.x;
  int stride = gridDim.x * 256;
  int total = n0 + n1 + n2;
  for (; i < total; i += stride) {
    const float* s; u16* d; int k = i;
    if (k < n0) { s = s0; d = d0; }
    else if (k < n0 + n1) { s = s1; d = d1; k -= n0; }
    else { s = s2; d = d2; k -= n0 + n1; }
    float4 v = ((const float4*)s)[k];
    ushort4 o;
    o.x = f2bf(v.x); o.y = f2bf(v.y); o.z = f2bf(v.z); o.w = f2bf(v.w);
    ((ushort4*)d)[k] = o;
  }
}

// ---------------- GEMM C = A * B^T  (A:[M,K], B:[N,K], bf16 in, fp32 acc) ----------------
// 1-D grid with XCD chunk remap (grid % 8 == 0).
template<int EPI>
__global__ __launch_bounds__(256)
void k_gemm(const u16* __restrict__ A, const u16* __restrict__ Bm,
            float* __restrict__ Cf, u16* __restrict__ Qr, u16* __restrict__ Kr, u16* __restrict__ Vr,
            int N, int K, int NX) {
  __shared__ alignas(16) char sA[128 * 128];
  __shared__ alignas(16) char sB[128 * 128];
  const int tid = threadIdx.x;
  const int wid = tid >> 6, lane = tid & 63;
  const int l15 = lane & 15, l4 = lane >> 4;
  const int nwg = gridDim.x, bid = blockIdx.x;
  const int wg = (bid & 7) * (nwg >> 3) + (bid >> 3);
  const int bx = wg % NX, by = wg / NX;
  const int m0 = by * 128, n0 = bx * 128;
  const int wr = (wid >> 1) * 64, wc = (wid & 1) * 64;

  f32x4 acc[4][4];
  #pragma unroll
  for (int i = 0; i < 4; ++i)
    #pragma unroll
    for (int j = 0; j < 4; ++j)
      acc[i][j] = (f32x4){0.f, 0.f, 0.f, 0.f};

  const int nkt = K >> 6;
  for (int kt = 0; kt < nkt; ++kt) {
    const int k0 = kt << 6;
    __syncthreads();
    #pragma unroll
    for (int it = 0; it < 4; ++it) {
      int o = it * 4096 + tid * 16;
      int row = o >> 7, cb = o & 127;
      int scb = cb ^ ((row & 7) << 4);
      gload_lds16((const char*)A + ((size_t)(m0 + row) * K + k0) * 2 + scb, &sA[it * 4096 + wid * 1024]);
    }
    #pragma unroll
    for (int it = 0; it < 4; ++it) {
      int o = it * 4096 + tid * 16;
      int row = o >> 7, cb = o & 127;
      int scb = cb ^ ((row & 7) << 4);
      gload_lds16((const char*)Bm + ((size_t)(n0 + row) * K + k0) * 2 + scb, &sB[it * 4096 + wid * 1024]);
    }
    __syncthreads();
    #pragma unroll
    for (int kk = 0; kk < 2; ++kk) {
      bf16x8 av[4], bv[4];
      #pragma unroll
      for (int mi = 0; mi < 4; ++mi) {
        int row = wr + mi * 16 + l15;
        int colb = kk * 64 + 16 * l4;
        av[mi] = *(const bf16x8*)&sA[row * 128 + (colb ^ ((row & 7) << 4))];
      }
      #pragma unroll
      for (int ni = 0; ni < 4; ++ni) {
        int row = wc + ni * 16 + l15;
        int colb = kk * 64 + 16 * l4;
        bv[ni] = *(const bf16x8*)&sB[row * 128 + (colb ^ ((row & 7) << 4))];
      }
      #pragma unroll
      for (int mi = 0; mi < 4; ++mi)
        #pragma unroll
        for (int ni = 0; ni < 4; ++ni)
          acc[mi][ni] = __builtin_amdgcn_mfma_f32_16x16x32_bf16(av[mi], bv[ni], acc[mi][ni], 0, 0, 0);
    }
  }

  #pragma unroll
  for (int mi = 0; mi < 4; ++mi) {
    #pragma unroll
    for (int ni = 0; ni < 4; ++ni) {
      #pragma unroll
      for (int j = 0; j < 4; ++j) {
        int gm = m0 + wr + mi * 16 + l4 * 4 + j;
        int gn = n0 + wc + ni * 16 + l15;
        float v = acc[mi][ni][j];
        if (EPI == 0) {
          int b = gm >> 11, l = gm & 2047;
          int which = gn >> 11, hid = gn & 2047;
          int h = hid >> 7, d = hid & 127;
          u16* dst = (which == 0) ? Qr : ((which == 1) ? Kr : Vr);
          size_t idx = ((size_t)(b * NH + h) * SEQ + l) * DH + d;
          dst[idx] = f2bf(v);
        } else {
          Cf[(size_t)gm * N + gn] = v;
        }
      }
    }
  }
}

// ---------------- V transpose: Vr[bh][l][d] -> Vt[bh][d][l] ----------------
__global__ __launch_bounds__(256) void k_vtr(const u16* __restrict__ Vr, u16* __restrict__ Vt) {
  __shared__ u16 tile[64][72];
  const int k0 = blockIdx.x * 64, d0 = blockIdx.y * 64, bh = blockIdx.z;
  const u16* src = Vr + ((size_t)bh << 18);
  u16* dst = Vt + ((size_t)bh << 18);
  const int tid = threadIdx.x;
  #pragma unroll
  for (int it = 0; it < 2; ++it) {
    int e = it * 2048 + tid * 8;
    int r = e >> 6, c = e & 63;
    bf16x8 v = *(const bf16x8*)(src + (size_t)(k0 + r) * DH + d0 + c);
    *(bf16x8*)&tile[r][c] = v;
  }
  __syncthreads();
  #pragma unroll
  for (int it = 0; it < 2; ++it) {
    int e = it * 2048 + tid * 8;
    int rd = e >> 6, ck = e & 63;
    bf16x8 w;
    #pragma unroll
    for (int i = 0; i < 8; ++i) w[i] = (short)tile[ck + i][rd];
    *(bf16x8*)(dst + (size_t)(d0 + rd) * SEQ + k0 + ck) = w;
  }
}

// -------- RMSNorm + interleaved RoPE, in place; blockIdx.y: 0 -> Q (mul=mq), 1 -> K --------
__global__ __launch_bounds__(256) void k_nrope2(u16* __restrict__ Qr, u16* __restrict__ Kr, float mq) {
  u16* T = blockIdx.y ? Kr : Qr;
  const float mul = blockIdx.y ? 1.0f : mq;
  const int r = blockIdx.x * 4 + (threadIdx.x >> 6);
  const int lane = threadIdx.x & 63;
  u16* p = T + ((size_t)r << 7) + lane * 2;
  u32 pr = *(const u32*)p;
  float xe = bf2f((u16)(pr & 0xffffu));
  float xo = bf2f((u16)(pr >> 16));
  float ss = xe * xe + xo * xo;
  #pragma unroll
  for (int off = 1; off < 64; off <<= 1) ss += __shfl_xor(ss, off);
  float rinv = rsqrtf(ss * (1.f / 128.f) + 1e-5f);
  float e = xe * rinv, o = xo * rinv;
  int pos = r & (SEQ - 1);
  float freq = exp2f(-0.20762050593046014f * (float)lane);
  float ang = (float)pos * freq;
  float sn, cs;
  sincosf(ang, &sn, &cs);
  u32 outw = (u32)f2bf((o * cs - e * sn) * mul) | ((u32)f2bf((o * sn + e * cs) * mul) << 16);
  *(u32*)p = outw;
}

// ---------------- causal flash attention ----------------
// Swapped QK^T (lane-local softmax rows), exp2 domain (scale*log2e folded into Q),
// defer-max rescale, dual-tile interleave with shared K/V register operands.

__device__ __forceinline__ void smax(f32x4 (&sacc)[4], float& m_, float& se,
                                     f32x4* accO, u32 (&pw)[8],
                                     bool diag, int qpos, int kb, int l15, int l4) {
  if (diag) {
    #pragma unroll
    for (int sj = 0; sj < 4; ++sj)
      #pragma unroll
      for (int j = 0; j < 4; ++j) {
        int kpos = kb + sj * 16 + l4 * 4 + j;
        if (kpos > qpos) sacc[sj][j] = -1e30f;
      }
  }
  float mx = sacc[0][0];
  #pragma unroll
  for (int sj = 0; sj < 4; ++sj)
    #pragma unroll
    for (int j = 0; j < 4; ++j) mx = fmaxf(mx, sacc[sj][j]);
  mx = fmaxf(mx, __shfl_xor(mx, 16));
  mx = fmaxf(mx, __shfl_xor(mx, 32));
  if (!__all(mx <= m_ + 8.f)) {
    float mn = fmaxf(m_, mx);
    float corr = __builtin_exp2f(m_ - mn);
    m_ = mn;
    se *= corr;
    float corr4[4];
    #pragma unroll
    for (int j = 0; j < 4; ++j) corr4[j] = __shfl(corr, l4 * 4 + j);
    #pragma unroll
    for (int db = 0; db < 8; ++db) {
      f32x4 a = accO[db];
      #pragma unroll
      for (int j = 0; j < 4; ++j) a[j] *= corr4[j];
      accO[db] = a;
    }
  }
  float sum = 0.f;
  #pragma unroll
  for (int sj = 0; sj < 4; ++sj)
    #pragma unroll
    for (int jp = 0; jp < 2; ++jp) {
      float p0 = __builtin_exp2f(sacc[sj][jp * 2]     - m_);
      float p1 = __builtin_exp2f(sacc[sj][jp * 2 + 1] - m_);
      pw[sj * 2 + jp] = (u32)f2bf(p0) | ((u32)f2bf(p1) << 16);
      sum += p0 + p1;
    }
  sum += __shfl_xor(sum, 16);
  sum += __shfl_xor(sum, 32);
  se += sum;
}

__device__ __forceinline__ void pwrite(char* sPw, const u32 (&pw)[8], int l15, int l4) {
  const int sw = (l15 & 7) << 4;
  char* base = sPw + l15 * 128;
  #pragma unroll
  for (int sj = 0; sj < 4; ++sj)
    #pragma unroll
    for (int jp = 0; jp < 2; ++jp)
      *(u32*)(base + ((sj * 32 + l4 * 8 + jp * 4) ^ sw)) = pw[sj * 2 + jp];
}

__device__ __forceinline__ void stage_kv(const char* Kp, const char* Vtp, int kb,
                                         char* bK, char* bV, int tid, int wid) {
  #pragma unroll
  for (int it = 0; it < 4; ++it) {
    int o = it * 4096 + tid * 16;
    int row = o >> 8, cb = o & 255;
    int scb = cb ^ ((row & 7) << 4);
    gload_lds16(Kp + (size_t)(kb + row) * 256 + scb, &bK[it * 4096 + wid * 1024]);
  }
  #pragma unroll
  for (int it = 0; it < 4; ++it) {
    int o = it * 4096 + tid * 16;
    int row = o >> 7, cb = o & 127;
    int scb = cb ^ ((row & 7) << 4);
    gload_lds16(Vtp + (size_t)row * (SEQ * 2) + kb * 2 + scb, &bV[it * 4096 + wid * 1024]);
  }
}

// grid: 512 blocks (XCD-remapped); block 256 = 4 waves. Pair p: q-tiles p and 31-p.
__global__ __launch_bounds__(256, 2)
void k_attn(const u16* __restrict__ Q, const u16* __restrict__ Kg,
            const u16* __restrict__ Vt, u16* __restrict__ O) {
  __shared__ alignas(16) char sK0[64 * 256];
  __shared__ alignas(16) char sK1[64 * 256];
  __shared__ alignas(16) char sV0[128 * 128];
  __shared__ alignas(16) char sV1[128 * 128];
  __shared__ alignas(16) char sP[4 * 2048];
  const int tid = threadIdx.x, wid = tid >> 6, lane = tid & 63;
  const int l15 = lane & 15, l4 = lane >> 4;
  const int i = blockIdx.x;
  const int xcd = i & 7, slot = i >> 3;
  const int p = slot & 15;
  const int bh = xcd + 8 * (slot >> 4);
  const int b = bh >> 4, h = bh & 15;
  const int tA = p, tB = 31 - p;
  const u16* Qp = Q + ((size_t)bh << 18);
  const char* Kp = (const char*)(Kg + ((size_t)bh << 18));
  const char* Vtp = (const char*)(Vt + ((size_t)bh << 18));
  const int q0A = tA * 64 + wid * 16;
  const int q0B = tB * 64 + wid * 16;

  bf16x8 aqA[4], aqB[4];
  #pragma unroll
  for (int kk = 0; kk < 4; ++kk) {
    aqA[kk] = *(const bf16x8*)(Qp + (size_t)(q0A + l15) * DH + kk * 32 + 8 * l4);
    aqB[kk] = *(const bf16x8*)(Qp + (size_t)(q0B + l15) * DH + kk * 32 + 8 * l4);
  }

  f32x4 accA[8], accB[8];
  #pragma unroll
  for (int i2 = 0; i2 < 8; ++i2) { accA[i2] = (f32x4){0.f,0.f,0.f,0.f}; accB[i2] = (f32x4){0.f,0.f,0.f,0.f}; }
  float mA = -1e30f, mB = -1e30f, seA = 0.f, seB = 0.f;

  char* sPw = sP + wid * 2048;
  const int psw = (l15 & 7) << 4;
  const int nt = tB + 1;

  stage_kv(Kp, Vtp, 0, sK0, sV0, tid, wid);
  for (int t = 0; t < nt; ++t) {
    char* bK = (t & 1) ? sK1 : sK0;
    char* bV = (t & 1) ? sV1 : sV0;
    if (t + 1 < nt) {
      stage_kv(Kp, Vtp, (t + 1) << 6, (t & 1) ? sK0 : sK1, (t & 1) ? sV0 : sV1, tid, wid);
      asm volatile("s_waitcnt vmcnt(8)" ::: "memory");
    } else {
      asm volatile("s_waitcnt vmcnt(0)" ::: "memory");
    }
    __builtin_amdgcn_sched_barrier(0);
    __builtin_amdgcn_s_barrier();

    const int kb = t << 6;
    if (t <= tA) {
      // ---- dual path: both sub-tiles, shared K/V operands, interleaved softmax ----
      f32x4 sb[4], sa[4];
      __builtin_amdgcn_s_setprio(1);
      #pragma unroll
      for (int sj = 0; sj < 4; ++sj) {
        sb[sj] = (f32x4){0.f,0.f,0.f,0.f};
        sa[sj] = (f32x4){0.f,0.f,0.f,0.f};
        int row = sj * 16 + l15;
        const char* rK = bK + (row << 8);
        int swr = (row & 7) << 4;
        #pragma unroll
        for (int kk = 0; kk < 4; ++kk) {
          bf16x8 bkv = *(const bf16x8*)(rK + ((kk * 64 + 16 * l4) ^ swr));
          sb[sj] = __builtin_amdgcn_mfma_f32_16x16x32_bf16(bkv, aqB[kk], sb[sj], 0, 0, 0);
          sa[sj] = __builtin_amdgcn_mfma_f32_16x16x32_bf16(bkv, aqA[kk], sa[sj], 0, 0, 0);
        }
      }
      __builtin_amdgcn_s_setprio(0);
      u32 pwB[8], pwA[8];
      smax(sb, mB, seB, accB, pwB, false, 0, kb, l15, l4);
      smax(sa, mA, seA, accA, pwA, t == tA, q0A + l15, kb, l15, l4);
      pwrite(sPw, pwB, l15, l4);
      bf16x8 paB0 = *(const bf16x8*)(sPw + l15 * 128 + ((16 * l4) ^ psw));
      bf16x8 paB1 = *(const bf16x8*)(sPw + l15 * 128 + ((64 + 16 * l4) ^ psw));
      pwrite(sPw, pwA, l15, l4);
      bf16x8 paA0 = *(const bf16x8*)(sPw + l15 * 128 + ((16 * l4) ^ psw));
      bf16x8 paA1 = *(const bf16x8*)(sPw + l15 * 128 + ((64 + 16 * l4) ^ psw));
      __builtin_amdgcn_s_setprio(1);
      #pragma unroll
      for (int db = 0; db < 8; ++db) {
        int row = db * 16 + l15;
        const char* vb = bV + row * 128;
        int swr = (row & 7) << 4;
        bf16x8 b0 = *(const bf16x8*)(vb + ((16 * l4) ^ swr));
        bf16x8 b1 = *(const bf16x8*)(vb + ((64 + 16 * l4) ^ swr));
        accB[db] = __builtin_amdgcn_mfma_f32_16x16x32_bf16(paB0, b0, accB[db], 0, 0, 0);
        accA[db] = __builtin_amdgcn_mfma_f32_16x16x32_bf16(paA0, b0, accA[db], 0, 0, 0);
        accB[db] = __builtin_amdgcn_mfma_f32_16x16x32_bf16(paB1, b1, accB[db], 0, 0, 0);
        accA[db] = __builtin_amdgcn_mfma_f32_16x16x32_bf16(paA1, b1, accA[db], 0, 0, 0);
      }
      __builtin_amdgcn_s_setprio(0);
    } else {
      // ---- single path: B only ----
      f32x4 sb[4];
      __builtin_amdgcn_s_setprio(1);
      #pragma unroll
      for (int sj = 0; sj < 4; ++sj) {
        sb[sj] = (f32x4){0.f,0.f,0.f,0.f};
        int row = sj * 16 + l15;
        const char* rK = bK + (row << 8);
        int swr = (row & 7) << 4;
        #pragma unroll
        for (int kk = 0; kk < 4; ++kk) {
          bf16x8 bkv = *(const bf16x8*)(rK + ((kk * 64 + 16 * l4) ^ swr));
          sb[sj] = __builtin_amdgcn_mfma_f32_16x16x32_bf16(bkv, aqB[kk], sb[sj], 0, 0, 0);
        }
      }
      __builtin_amdgcn_s_setprio(0);
      u32 pwB[8];
      smax(sb, mB, seB, accB, pwB, t == tB, q0B + l15, kb, l15, l4);
      pwrite(sPw, pwB, l15, l4);
      bf16x8 paB0 = *(const bf16x8*)(sPw + l15 * 128 + ((16 * l4) ^ psw));
      bf16x8 paB1 = *(const bf16x8*)(sPw + l15 * 128 + ((64 + 16 * l4) ^ psw));
      __builtin_amdgcn_s_setprio(1);
      #pragma unroll
      for (int db = 0; db < 8; ++db) {
        int row = db * 16 + l15;
        const char* vb = bV + row * 128;
        int swr = (row & 7) << 4;
        bf16x8 b0 = *(const bf16x8*)(vb + ((16 * l4) ^ swr));
        bf16x8 b1 = *(const bf16x8*)(vb + ((64 + 16 * l4) ^ swr));
        accB[db] = __builtin_amdgcn_mfma_f32_16x16x32_bf16(paB0, b0, accB[db], 0, 0, 0);
        accB[db] = __builtin_amdgcn_mfma_f32_16x16x32_bf16(paB1, b1, accB[db], 0, 0, 0);
      }
      __builtin_amdgcn_s_setprio(0);
    }

    __builtin_amdgcn_s_barrier();
  }

  float seA4[4], seB4[4];
  #pragma unroll
  for (int j = 0; j < 4; ++j) {
    seA4[j] = __shfl(seA, l4 * 4 + j);
    seB4[j] = __shfl(seB, l4 * 4 + j);
  }
  #pragma unroll
  for (int db = 0; db < 8; ++db) {
    #pragma unroll
    for (int j = 0; j < 4; ++j) {
      int d = db * 16 + l15;
      int qA = q0A + l4 * 4 + j;
      int qB = q0B + l4 * 4 + j;
      O[(size_t)(b * SEQ + qA) * HID + h * DH + d] = f2bf(accA[db][j] / seA4[j]);
      O[(size_t)(b * SEQ + qB) * HID + h * DH + d] = f2bf(accB[db][j] / seB4[j]);
    }
  }
}

extern "C" void kernel_launch(void* const* d_in, const int* in_sizes, int n_in,
                              void* d_out, int out_size, void* d_ws, size_t ws_size,
                              hipStream_t stream) {
  (void)in_sizes; (void)n_in; (void)out_size; (void)ws_size;
  const float* x = (const float*)d_in[0];
  const float* Wqkv = (const float*)d_in[1];
  const float* Wout = (const float*)d_in[2];
  float* out = (float*)d_out;
  char* ws = (char*)d_ws;

  u16* xb  = (u16*)(ws);                                   // 16 MB [4096][2048] bf16 (also attn O)
  u16* wqb = (u16*)(ws + (size_t)16777216);                // 24 MB [6144][2048] bf16
  u16* Vt  = wqb;                                          // aliases wqb AFTER gemm0 (16 MB)
  u16* wob = (u16*)(ws + (size_t)16777216 + 25165824);     // 8 MB  [2048][2048] bf16
  u16* Qr  = (u16*)(ws + (size_t)50331648);                // 16 MB each (8388608 u16 elements)
  u16* Kr  = Qr + (size_t)8388608;
  u16* Vr  = Kr + (size_t)8388608;
  u16* Ob  = xb;

  // q pre-scale: (1/sqrt(128)) * log2(e)  -> softmax in exp2 domain
  const float mq = 0.08838834764831845f * 1.4426950408889634f;

  k_cvt3<<<dim3(2048), dim3(256), 0, stream>>>(x, xb, (NB * SEQ * HID) / 4,
                                               Wqkv, wqb, (3 * HID * HID) / 4,
                                               Wout, wob, (HID * HID) / 4);

  k_gemm<0><<<dim3(1536), dim3(256), 0, stream>>>(xb, wqb, nullptr, Qr, Kr, Vr, 3 * HID, HID, 48);

  k_vtr<<<dim3(SEQ / 64, DH / 64, NB * NH), dim3(256), 0, stream>>>(Vr, Vt);
  k_nrope2<<<dim3((NB * NH * SEQ) / 4, 2), dim3(256), 0, stream>>>(Qr, Kr, mq);

  k_attn<<<dim3(512), dim3(256), 0, stream>>>(Qr, Kr, Vt, Ob);

  k_gemm<1><<<dim3(512), dim3(256), 0, stream>>>(Ob, wob, out, nullptr, nullptr, nullptr, HID, HID, 16);
}